// Round 7
// baseline (200.954 us; speedup 1.0000x reference)
//
#include <hip/hip_runtime.h>
#include <hip/hip_bf16.h>

#define NTOK 2048
#define HDIM 1024
#define DDIM 1024
#define NEXP 8
#define MAXMB 40

typedef __bf16 bf16x8 __attribute__((ext_vector_type(8)));
typedef float f32x4 __attribute__((ext_vector_type(4)));

__device__ __forceinline__ f32x4 mfma16(bf16x8 a, bf16x8 b, f32x4 c) {
  return __builtin_amdgcn_mfma_f32_16x16x32_bf16(a, b, c, 0, 0, 0);
}

__device__ __forceinline__ void async_copy16(const void* g, void* l) {
  __builtin_amdgcn_global_load_lds(
      (const __attribute__((address_space(1))) void*)g,
      (__attribute__((address_space(3))) void*)l, 16, 0, 0);
}

// -------- prep: router only (weight transpose+convert is fused into the GEMMs) --------
__global__ __launch_bounds__(256) void prep_kernel(
    const float* __restrict__ x, const float* __restrict__ rw,
    __bf16* __restrict__ xb,
    unsigned int* __restrict__ top_pack, float2* __restrict__ top_w)
{
  int wave = threadIdx.x >> 6, lane = threadIdx.x & 63;
  int n = blockIdx.x * 4 + wave;
  const float* xr = x + (size_t)n * HDIM;
  float acc[NEXP];
#pragma unroll
  for (int e = 0; e < NEXP; ++e) acc[e] = 0.f;
  float xv[16];
#pragma unroll
  for (int i = 0; i < 16; ++i) {
    int h = lane + 64 * i;
    float v = xr[h];
    xv[i] = v;
#pragma unroll
    for (int e = 0; e < NEXP; ++e) acc[e] += v * rw[e * HDIM + h];
  }
#pragma unroll
  for (int e = 0; e < NEXP; ++e) {
    float v = acc[e];
#pragma unroll
    for (int off = 32; off > 0; off >>= 1) v += __shfl_xor(v, off, 64);
    acc[e] = v;
  }
#pragma unroll
  for (int i = 0; i < 16; ++i)
    xb[(size_t)n * HDIM + lane + 64 * i] = (__bf16)xv[i];

  if (lane == 0) {
    int i1 = 0; float l1 = acc[0];
#pragma unroll
    for (int e = 1; e < NEXP; ++e) if (acc[e] > l1) { l1 = acc[e]; i1 = e; }
    int i2 = -1; float l2 = -3.4e38f;
#pragma unroll
    for (int e = 0; e < NEXP; ++e) if (e != i1 && acc[e] > l2) { l2 = acc[e]; i2 = e; }
    float m = fmaxf(l1, l2);
    float p1 = __expf(l1 - m), p2 = __expf(l2 - m);
    float inv = 1.f / (p1 + p2);
    top_pack[n] = (unsigned int)i1 | ((unsigned int)i2 << 8);
    top_w[n] = make_float2(p1 * inv, p2 * inv);
  }
}

// -------- compact: one block per expert, LDS counter -> counts + tok_list ---------------
__global__ __launch_bounds__(256) void compact_kernel(
    const unsigned int* __restrict__ top_pack,
    int* __restrict__ counts, int* __restrict__ tok_list)
{
  int e = blockIdx.x;
  __shared__ int cnt;
  if (threadIdx.x == 0) cnt = 0;
  __syncthreads();
  for (int n = threadIdx.x; n < NTOK; n += 256) {
    unsigned int p = top_pack[n];
    int e1 = p & 255, e2 = (p >> 8) & 255;
    if (e1 == e) { int pos = atomicAdd(&cnt, 1); tok_list[e * NTOK + pos] = 2 * n; }
    if (e2 == e) { int pos = atomicAdd(&cnt, 1); tok_list[e * NTOK + pos] = 2 * n + 1; }
  }
  __syncthreads();
  if (threadIdx.x == 0) counts[e] = cnt;
}

// -------- gathered GEMM, 128x128x64, fused fp32->bf16 transpose B-staging --------------
// B comes straight from the original fp32 weights: per K-step each thread loads 8 f32x4
// (wave instr = 512B dense segments), packs bf16 k-pairs, ds_write_b128 into the same
// swizzled LDS image as before (MFMA loop unchanged). SYNC IS ORDER-INDEPENDENT:
// drain vmcnt(0)+lgkmcnt(0) covers ds_writes + A-copies regardless of scheduler order;
// the B(it+1) prefetch is issued AFTER the drain (can't hoist above asm memory clobber)
// and overlaps the 32-MFMA compute phase. No counted vmcnt (R6's NaN root cause).
// IS_UP: B rows 0-63 = gate cols, 64-127 = up cols (same d range) -> SwiGLU -> hidden.
// !IS_UP: fused combine: out[tok] += gate_weight * acc via fp32 atomicAdd (exactly 2
// contributions per element, no contention; out pre-zeroed by memsetAsync).
template<bool IS_UP>
__device__ __forceinline__ void gemm_body(
    const __bf16* __restrict__ Atok, const float* __restrict__ W,
    const int* __restrict__ counts, const int* __restrict__ tok_list,
    __bf16* __restrict__ hidden, float* __restrict__ out,
    const float2* __restrict__ top_w,
    int mb, int n0,
    __bf16* As, __bf16* Bs, int* rows_s)
{
  const int NCS = IS_UP ? 2048 : 1024;   // fp32 source row length
  int e = -1, m0 = 0, base = 0;
#pragma unroll
  for (int i = 0; i < NEXP; ++i) {
    int c = counts[i];
    int nt = (c + 127) >> 7;
    if (e < 0 && mb < base + nt) { e = i; m0 = (mb - base) << 7; }
    base += nt;
  }
  if (e < 0) return;
  int nrows = counts[e];

  int t = threadIdx.x;
  if (t < 128) {
    int idx = m0 + t;
    rows_s[t] = (idx < nrows) ? tok_list[e * NTOK + idx] : -1;
  }
  __syncthreads();

  int w = t >> 6, lane = t & 63;
  int lm = lane & 15, quad = lane >> 4;

  // A staging pointers (token gather via global_load_lds, unchanged layout)
  const __bf16* pA[4];
#pragma unroll
  for (int j = 0; j < 4; ++j) {
    int s = j * 256 + t;
    int r = s >> 3;
    int cg = (s & 7) ^ (r & 7);
    int rid = rows_s[r];
    int arow = (rid < 0) ? 0 : (IS_UP ? (rid >> 1) : rid);
    pA[j] = Atok + (size_t)arow * 1024 + cg * 8;
  }

  // B staging geometry: thread owns k-chunk cB (8 k-rows) x image rows r0..r0+3
  int cB = t >> 5;            // 0..7
  int r0 = (t & 31) * 4;      // 0..124
  int csrc = IS_UP ? ((r0 < 64) ? (n0 >> 1) + r0 : 1024 + (n0 >> 1) + (r0 - 64))
                   : n0 + r0;
  const float* Bsrc = W + ((size_t)e * 1024 + cB * 8) * NCS + csrc;
  int bwoff[4];
#pragma unroll
  for (int j = 0; j < 4; ++j)
    bwoff[j] = (r0 + j) * 128 + ((cB ^ ((r0 + j) & 7)) * 16);

  f32x4 acc[2][8];
#pragma unroll
  for (int i = 0; i < 2; ++i)
#pragma unroll
    for (int j = 0; j < 8; ++j) acc[i][j] = (f32x4){0.f, 0.f, 0.f, 0.f};

  f32x4 v[8];
#pragma unroll
  for (int i = 0; i < 8; ++i)              // prologue: B(0) in flight
    v[i] = *(const f32x4*)(Bsrc + (size_t)i * NCS);

  const int NT = 16;                       // K = 1024, 64 per step
  for (int it = 0; it < NT; ++it) {
    // pack B(it) to bf16 k-pairs (compiler inserts the vmcnt wait on v here)
    uint4 pk[4];
#pragma unroll
    for (int j = 0; j < 4; ++j) {
      union { unsigned int u; __bf16 h[2]; } p0, p1, p2, p3;
      p0.h[0] = (__bf16)v[0][j]; p0.h[1] = (__bf16)v[1][j];
      p1.h[0] = (__bf16)v[2][j]; p1.h[1] = (__bf16)v[3][j];
      p2.h[0] = (__bf16)v[4][j]; p2.h[1] = (__bf16)v[5][j];
      p3.h[0] = (__bf16)v[6][j]; p3.h[1] = (__bf16)v[7][j];
      pk[j] = make_uint4(p0.u, p1.u, p2.u, p3.u);
    }
    __builtin_amdgcn_s_barrier();          // all waves done reading LDS of step it-1
    __builtin_amdgcn_sched_barrier(0);     // nothing crosses the barrier
#pragma unroll
    for (int j = 0; j < 4; ++j)
      *(uint4*)((char*)Bs + bwoff[j]) = pk[j];
#pragma unroll
    for (int j = 0; j < 4; ++j)
      async_copy16(pA[j] + it * 64, (char*)As + (j * 256 + w * 64) * 16);
    // order-independent drain: A-copies + ds_writes done, whatever the issue order
    asm volatile("s_waitcnt vmcnt(0) lgkmcnt(0)" ::: "memory");
    if (it + 1 < NT) {
#pragma unroll
      for (int i = 0; i < 8; ++i)          // B(it+1): issued after drain, flies over MFMA
        v[i] = *(const f32x4*)(Bsrc + (size_t)((it + 1) * 64 + i) * NCS);
    }
    __builtin_amdgcn_s_barrier();          // stage(it) visible to all waves
    __builtin_amdgcn_sched_barrier(0);     // keep ds_reads below the barrier

#pragma unroll
    for (int kk = 0; kk < 2; ++kk) {
      bf16x8 a[2], b[8];
#pragma unroll
      for (int i = 0; i < 2; ++i) {
        int R = w * 32 + i * 16 + lm;
        int c = (quad + kk * 4) ^ (R & 7);
        a[i] = *(const bf16x8*)((char*)As + (size_t)(R * 8 + c) * 16);
      }
#pragma unroll
      for (int j = 0; j < 8; ++j) {
        int R = j * 16 + lm;
        int c = (quad + kk * 4) ^ (R & 7);
        b[j] = *(const bf16x8*)((char*)Bs + (size_t)(R * 8 + c) * 16);
      }
#pragma unroll
      for (int i = 0; i < 2; ++i)
#pragma unroll
        for (int j = 0; j < 8; ++j)
          acc[i][j] = mfma16(a[i], b[j], acc[i][j]);
    }
  }

  if (IS_UP) {
    int dbase = n0 >> 1;   // 64 unique d per 128-wide tile
#pragma unroll
    for (int i = 0; i < 2; ++i)
#pragma unroll
      for (int r = 0; r < 4; ++r) {
        int lr = w * 32 + i * 16 + quad * 4 + r;     // C/D: row = quad*4+reg
        int rid = rows_s[lr];
        if (rid >= 0) {
#pragma unroll
          for (int j = 0; j < 4; ++j) {
            float g = acc[i][j][r];
            float u = acc[i][j + 4][r];
            float hv = g / (1.f + __expf(-g)) * u;
            hidden[(size_t)rid * DDIM + dbase + j * 16 + lm] = (__bf16)hv;
          }
        }
      }
  } else {
#pragma unroll
    for (int i = 0; i < 2; ++i)
#pragma unroll
      for (int r = 0; r < 4; ++r) {
        int lr = w * 32 + i * 16 + quad * 4 + r;
        int rid = rows_s[lr];
        if (rid >= 0) {
          float2 tw = top_w[rid >> 1];
          float wt = (rid & 1) ? tw.y : tw.x;
          float* orow = out + (size_t)(rid >> 1) * HDIM + n0;
#pragma unroll
          for (int j = 0; j < 8; ++j)
            atomicAdd(orow + j * 16 + lm, acc[i][j][r] * wt);
        }
      }
  }
}

// -------- up-GEMM: 640 blocks, ny = b&15 -> XCD = ny%8 (B-panel L2 locality) -----------
__global__ __launch_bounds__(256, 3) void up_kernel(
    const __bf16* __restrict__ xb, const float* __restrict__ wup,
    const int* __restrict__ counts, const int* __restrict__ tok_list,
    __bf16* __restrict__ hidden)
{
  __shared__ __align__(16) char smem[33280];
  __bf16* As = (__bf16*)smem;
  __bf16* Bs = (__bf16*)(smem + 16384);
  int* rows_s = (int*)(smem + 32768);
  int b = blockIdx.x;
  gemm_body<true>(xb, wup, counts, tok_list, hidden, (float*)nullptr,
                  (const float2*)nullptr, b >> 4, (b & 15) * 128, As, Bs, rows_s);
}

// -------- down: grid (8 ny, 40 mb), fused gated atomic combine into out ----------------
__global__ __launch_bounds__(256, 3) void down_kernel(
    const __bf16* __restrict__ hidden, const float* __restrict__ wdn,
    const int* __restrict__ counts, const int* __restrict__ tok_list,
    const float2* __restrict__ top_w, float* __restrict__ out)
{
  __shared__ __align__(16) char smem[33280];
  __bf16* As = (__bf16*)smem;
  __bf16* Bs = (__bf16*)(smem + 16384);
  int* rows_s = (int*)(smem + 32768);
  gemm_body<false>(hidden, wdn, counts, tok_list, (__bf16*)nullptr, out, top_w,
                   blockIdx.y, blockIdx.x * 128, As, Bs, rows_s);
}

extern "C" void kernel_launch(void* const* d_in, const int* in_sizes, int n_in,
                              void* d_out, int out_size, void* d_ws, size_t ws_size,
                              hipStream_t stream) {
  const float* x  = (const float*)d_in[0];
  const float* rw = (const float*)d_in[1];
  const float* up = (const float*)d_in[2];
  const float* dw = (const float*)d_in[3];
  float* out = (float*)d_out;

  char* ws = (char*)d_ws;
  int* counts          = (int*)ws;                             // 32 B
  int* tok_list        = (int*)(ws + 4096);                    // 64 KB
  unsigned int* top_pk = (unsigned int*)(ws + (256u << 10));   // 8 KB  @ 256 KB
  float2* top_w        = (float2*)(ws + (272u << 10));         // 16 KB @ 272 KB
  __bf16* xb           = (__bf16*)(ws + (1u << 20));           // 4 MB  @ 1 MB
  __bf16* hidden       = (__bf16*)(ws + (8u << 20));           // 8 MB  @ 8 MB
  (void)ws_size; (void)n_in; (void)in_sizes; (void)out_size;

  hipMemsetAsync(out, 0, (size_t)NTOK * HDIM * sizeof(float), stream);
  prep_kernel<<<NTOK / 4, 256, 0, stream>>>(x, rw, xb, top_pk, top_w);
  compact_kernel<<<NEXP, 256, 0, stream>>>(top_pk, counts, tok_list);
  up_kernel<<<640, 256, 0, stream>>>(xb, up, counts, tok_list, hidden);
  down_kernel<<<dim3(8, MAXMB), 256, 0, stream>>>(
      hidden, dw, counts, tok_list, top_w, out);
}

// Round 8
// 198.746 us; speedup vs baseline: 1.0111x; 1.0111x over previous
//
#include <hip/hip_runtime.h>
#include <hip/hip_bf16.h>

#define NTOK 2048
#define HDIM 1024
#define DDIM 1024
#define NEXP 8
#define MAXMB 40

typedef __bf16 bf16x8 __attribute__((ext_vector_type(8)));
typedef float f32x4 __attribute__((ext_vector_type(4)));

__device__ __forceinline__ f32x4 mfma16(bf16x8 a, bf16x8 b, f32x4 c) {
  return __builtin_amdgcn_mfma_f32_16x16x32_bf16(a, b, c, 0, 0, 0);
}

__device__ __forceinline__ void async_copy16(const void* g, void* l) {
  __builtin_amdgcn_global_load_lds(
      (const __attribute__((address_space(1))) void*)g,
      (__attribute__((address_space(3))) void*)l, 16, 0, 0);
}

// -------- setup: router + zero `out` (for down's atomic combine). 512 blocks. ----------
__global__ __launch_bounds__(256) void setup_kernel(
    const float* __restrict__ x, const float* __restrict__ rw,
    __bf16* __restrict__ xb,
    unsigned int* __restrict__ top_pack, float2* __restrict__ top_w,
    float* __restrict__ out)
{
  // zero 16KB slice of out (4096 floats per block)
  f32x4 z = (f32x4){0.f, 0.f, 0.f, 0.f};
#pragma unroll
  for (int i = 0; i < 4; ++i)
    ((f32x4*)out)[(size_t)blockIdx.x * 1024 + i * 256 + threadIdx.x] = z;

  int wave = threadIdx.x >> 6, lane = threadIdx.x & 63;
  int n = blockIdx.x * 4 + wave;
  const float* xr = x + (size_t)n * HDIM;
  float acc[NEXP];
#pragma unroll
  for (int e = 0; e < NEXP; ++e) acc[e] = 0.f;
  float xv[16];
#pragma unroll
  for (int i = 0; i < 16; ++i) {
    int h = lane + 64 * i;
    float v = xr[h];
    xv[i] = v;
#pragma unroll
    for (int e = 0; e < NEXP; ++e) acc[e] += v * rw[e * HDIM + h];
  }
#pragma unroll
  for (int e = 0; e < NEXP; ++e) {
    float v = acc[e];
#pragma unroll
    for (int off = 32; off > 0; off >>= 1) v += __shfl_xor(v, off, 64);
    acc[e] = v;
  }
#pragma unroll
  for (int i = 0; i < 16; ++i)
    xb[(size_t)n * HDIM + lane + 64 * i] = (__bf16)xv[i];

  if (lane == 0) {
    int i1 = 0; float l1 = acc[0];
#pragma unroll
    for (int e = 1; e < NEXP; ++e) if (acc[e] > l1) { l1 = acc[e]; i1 = e; }
    int i2 = -1; float l2 = -3.4e38f;
#pragma unroll
    for (int e = 0; e < NEXP; ++e) if (e != i1 && acc[e] > l2) { l2 = acc[e]; i2 = e; }
    float m = fmaxf(l1, l2);
    float p1 = __expf(l1 - m), p2 = __expf(l2 - m);
    float inv = 1.f / (p1 + p2);
    top_pack[n] = (unsigned int)i1 | ((unsigned int)i2 << 8);
    top_w[n] = make_float2(p1 * inv, p2 * inv);
  }
}

// -------- compact: one block per expert, LDS counter -> counts + tok_list ---------------
__global__ __launch_bounds__(256) void compact_kernel(
    const unsigned int* __restrict__ top_pack,
    int* __restrict__ counts, int* __restrict__ tok_list)
{
  int e = blockIdx.x;
  __shared__ int cnt;
  if (threadIdx.x == 0) cnt = 0;
  __syncthreads();
  for (int n = threadIdx.x; n < NTOK; n += 256) {
    unsigned int p = top_pack[n];
    int e1 = p & 255, e2 = (p >> 8) & 255;
    if (e1 == e) { int pos = atomicAdd(&cnt, 1); tok_list[e * NTOK + pos] = 2 * n; }
    if (e2 == e) { int pos = atomicAdd(&cnt, 1); tok_list[e * NTOK + pos] = 2 * n + 1; }
  }
  __syncthreads();
  if (threadIdx.x == 0) counts[e] = cnt;
}

// -------- gathered GEMM, 128x128x64, fused fp32->bf16 B-staging, A double-buffered -----
// Pipeline per K-step: pack B(it) | barrier | ds_write B | issue B(it+1) loads | issue
// A(it+1) copies into As[other] | vmcnt(12)+lgkmcnt(0) | barrier | compute As[it&1],Bs.
// vmcnt(12) is cross-step-safe by pure counting: current step issues exactly 12 VMEM ops
// (8 B-loads THEN 4 A-copies, order pinned by sched_barrier), so <=12 outstanding ==>
// all prior-step ops (incl. A(it)) retired. B-loads precede A-copies so the compiler's
// pack-wait is vmcnt(4), leaving A(it+1) in flight the whole step.
// B LDS image slot = cB ^ (r&7) ^ ((r>>2)&3): write instrs hit all 8 bank groups (min
// 8 acc/bank), reads stay uniform (enumerated). A image/layout unchanged (HW-linear).
// IS_UP: 4 waves x (32x128), SwiGLU in-lane (gate cols 0-63, up 64-127) -> hidden bf16.
// !IS_UP: 4 waves x (64x64) (20% fewer LDS reads); gated fp32 atomicAdd into out.
template<bool IS_UP>
__device__ __forceinline__ void gemm_body(
    const __bf16* __restrict__ Atok, const float* __restrict__ W,
    const int* __restrict__ counts, const int* __restrict__ tok_list,
    __bf16* __restrict__ hidden, float* __restrict__ out,
    const float2* __restrict__ top_w,
    int mb, int n0,
    __bf16* As, __bf16* Bs, int* rows_s)
{
  const int NCS = IS_UP ? 2048 : 1024;   // fp32 source row length
  constexpr int MI = IS_UP ? 2 : 4;      // A fragments per wave
  constexpr int NJ = IS_UP ? 8 : 4;      // B fragments per wave
  int e = -1, m0 = 0, base = 0;
#pragma unroll
  for (int i = 0; i < NEXP; ++i) {
    int c = counts[i];
    int nt = (c + 127) >> 7;
    if (e < 0 && mb < base + nt) { e = i; m0 = (mb - base) << 7; }
    base += nt;
  }
  if (e < 0) return;
  int nrows = counts[e];

  int t = threadIdx.x;
  if (t < 128) {
    int idx = m0 + t;
    rows_s[t] = (idx < nrows) ? tok_list[e * NTOK + idx] : -1;
  }
  __syncthreads();

  int w = t >> 6, lane = t & 63;
  int lm = lane & 15, quad = lane >> 4;
  int rowbase = IS_UP ? (w * 32) : ((w >> 1) * 64);
  int colbase = IS_UP ? 0 : ((w & 1) * 64);

  // A staging pointers (token gather via global_load_lds, unchanged layout)
  const __bf16* pA[4];
#pragma unroll
  for (int j = 0; j < 4; ++j) {
    int s = j * 256 + t;
    int r = s >> 3;
    int cg = (s & 7) ^ (r & 7);
    int rid = rows_s[r];
    int arow = (rid < 0) ? 0 : (IS_UP ? (rid >> 1) : rid);
    pA[j] = Atok + (size_t)arow * 1024 + cg * 8;
  }

  // B staging geometry: thread owns k-chunk cB (8 k-rows) x image rows r0..r0+3
  int cB = t >> 5;            // 0..7
  int r0 = (t & 31) * 4;      // 0..124
  int csrc = IS_UP ? ((r0 < 64) ? (n0 >> 1) + r0 : 1024 + (n0 >> 1) + (r0 - 64))
                   : n0 + r0;
  const float* Bsrc = W + ((size_t)e * 1024 + cB * 8) * NCS + csrc;
  int bwoff[4];
#pragma unroll
  for (int j = 0; j < 4; ++j) {
    int r = r0 + j;
    bwoff[j] = r * 128 + ((cB ^ (r & 7) ^ ((r >> 2) & 3)) * 16);
  }

  f32x4 acc[MI][NJ];
#pragma unroll
  for (int i = 0; i < MI; ++i)
#pragma unroll
    for (int j = 0; j < NJ; ++j) acc[i][j] = (f32x4){0.f, 0.f, 0.f, 0.f};

  // prologue: B(0) loads FIRST, then A(0) copies (B older => pack waits vmcnt(4))
  f32x4 v[8];
#pragma unroll
  for (int i = 0; i < 8; ++i)
    v[i] = *(const f32x4*)(Bsrc + (size_t)i * NCS);
  __builtin_amdgcn_sched_barrier(0);
#pragma unroll
  for (int j = 0; j < 4; ++j)
    async_copy16(pA[j], (char*)As + (j * 256 + w * 64) * 16);

  const int NT = 16;                     // K = 1024, 64 per step
  for (int it = 0; it < NT; ++it) {
    // pack B(it): compiler waits on v's loads only (they're the oldest)
    uint4 pk[4];
#pragma unroll
    for (int j = 0; j < 4; ++j) {
      union { unsigned int u; __bf16 h[2]; } p0, p1, p2, p3;
      p0.h[0] = (__bf16)v[0][j]; p0.h[1] = (__bf16)v[1][j];
      p1.h[0] = (__bf16)v[2][j]; p1.h[1] = (__bf16)v[3][j];
      p2.h[0] = (__bf16)v[4][j]; p2.h[1] = (__bf16)v[5][j];
      p3.h[0] = (__bf16)v[6][j]; p3.h[1] = (__bf16)v[7][j];
      pk[j] = make_uint4(p0.u, p1.u, p2.u, p3.u);
    }
    __builtin_amdgcn_s_barrier();        // all waves done reading LDS of step it-1
    __builtin_amdgcn_sched_barrier(0);
#pragma unroll
    for (int j = 0; j < 4; ++j)
      *(uint4*)((char*)Bs + bwoff[j]) = pk[j];
    if (it + 1 < NT) {
      __builtin_amdgcn_sched_barrier(0);
#pragma unroll
      for (int i = 0; i < 8; ++i)        // B(it+1): 8 loads, issued first
        v[i] = *(const f32x4*)(Bsrc + (size_t)((it + 1) * 64 + i) * NCS);
      __builtin_amdgcn_sched_barrier(0);
#pragma unroll
      for (int j = 0; j < 4; ++j)        // A(it+1): 4 copies into the other buffer
        async_copy16(pA[j] + (it + 1) * 64,
                     (char*)As + ((it + 1) & 1) * 16384 + (j * 256 + w * 64) * 16);
      __builtin_amdgcn_sched_barrier(0);
      // 12 ops issued this step => <=12 outstanding means A(it) + everything older done
      asm volatile("s_waitcnt vmcnt(12) lgkmcnt(0)" ::: "memory");
    } else {
      asm volatile("s_waitcnt vmcnt(0) lgkmcnt(0)" ::: "memory");
    }
    __builtin_amdgcn_s_barrier();        // stage(it) visible to all waves
    __builtin_amdgcn_sched_barrier(0);

    const char* Ab = (const char*)As + (it & 1) * 16384;
#pragma unroll
    for (int kk = 0; kk < 2; ++kk) {
      bf16x8 a[MI], b[NJ];
#pragma unroll
      for (int i = 0; i < MI; ++i) {
        int R = rowbase + i * 16 + lm;
        int c = (quad + kk * 4) ^ (R & 7);
        a[i] = *(const bf16x8*)(Ab + (size_t)(R * 8 + c) * 16);
      }
#pragma unroll
      for (int j = 0; j < NJ; ++j) {
        int R = colbase + j * 16 + lm;
        int c = (quad + kk * 4) ^ (R & 7) ^ ((R >> 2) & 3);
        b[j] = *(const bf16x8*)((char*)Bs + (size_t)(R * 8 + c) * 16);
      }
#pragma unroll
      for (int i = 0; i < MI; ++i)
#pragma unroll
        for (int j = 0; j < NJ; ++j)
          acc[i][j] = mfma16(a[i], b[j], acc[i][j]);
    }
  }

  if (IS_UP) {
    int dbase = n0 >> 1;   // 64 unique d per 128-wide tile
#pragma unroll
    for (int i = 0; i < MI; ++i)
#pragma unroll
      for (int r = 0; r < 4; ++r) {
        int lr = rowbase + i * 16 + quad * 4 + r;    // C/D: row = quad*4+reg
        int rid = rows_s[lr];
        if (rid >= 0) {
#pragma unroll
          for (int j = 0; j < 4; ++j) {
            float g = acc[i][j][r];
            float u = acc[i][j + 4][r];
            float hv = g / (1.f + __expf(-g)) * u;
            hidden[(size_t)rid * DDIM + dbase + j * 16 + lm] = (__bf16)hv;
          }
        }
      }
  } else {
#pragma unroll
    for (int i = 0; i < MI; ++i)
#pragma unroll
      for (int r = 0; r < 4; ++r) {
        int lr = rowbase + i * 16 + quad * 4 + r;
        int rid = rows_s[lr];
        if (rid >= 0) {
          float2 tw = top_w[rid >> 1];
          float wt = (rid & 1) ? tw.y : tw.x;
          float* orow = out + (size_t)(rid >> 1) * HDIM + n0 + colbase;
#pragma unroll
          for (int j = 0; j < NJ; ++j)
            atomicAdd(orow + j * 16 + lm, acc[i][j][r] * wt);
        }
      }
  }
}

// -------- up-GEMM: 640 blocks, ny = b&15 -> XCD = ny%8 (B-panel L2 locality) -----------
__global__ __launch_bounds__(256, 3) void up_kernel(
    const __bf16* __restrict__ xb, const float* __restrict__ wup,
    const int* __restrict__ counts, const int* __restrict__ tok_list,
    __bf16* __restrict__ hidden)
{
  __shared__ __align__(16) char smem[49664];   // As 2x16K | Bs 16K | rows_s 512
  __bf16* As = (__bf16*)smem;
  __bf16* Bs = (__bf16*)(smem + 32768);
  int* rows_s = (int*)(smem + 49152);
  int b = blockIdx.x;
  gemm_body<true>(xb, wup, counts, tok_list, hidden, (float*)nullptr,
                  (const float2*)nullptr, b >> 4, (b & 15) * 128, As, Bs, rows_s);
}

// -------- down: grid (8 ny, 40 mb), fused gated atomic combine into out ----------------
__global__ __launch_bounds__(256, 3) void down_kernel(
    const __bf16* __restrict__ hidden, const float* __restrict__ wdn,
    const int* __restrict__ counts, const int* __restrict__ tok_list,
    const float2* __restrict__ top_w, float* __restrict__ out)
{
  __shared__ __align__(16) char smem[49664];
  __bf16* As = (__bf16*)smem;
  __bf16* Bs = (__bf16*)(smem + 32768);
  int* rows_s = (int*)(smem + 49152);
  gemm_body<false>(hidden, wdn, counts, tok_list, (__bf16*)nullptr, out, top_w,
                   blockIdx.y, blockIdx.x * 128, As, Bs, rows_s);
}

extern "C" void kernel_launch(void* const* d_in, const int* in_sizes, int n_in,
                              void* d_out, int out_size, void* d_ws, size_t ws_size,
                              hipStream_t stream) {
  const float* x  = (const float*)d_in[0];
  const float* rw = (const float*)d_in[1];
  const float* up = (const float*)d_in[2];
  const float* dw = (const float*)d_in[3];
  float* out = (float*)d_out;

  char* ws = (char*)d_ws;
  int* counts          = (int*)ws;                             // 32 B
  int* tok_list        = (int*)(ws + 4096);                    // 64 KB
  unsigned int* top_pk = (unsigned int*)(ws + (256u << 10));   // 8 KB  @ 256 KB
  float2* top_w        = (float2*)(ws + (272u << 10));         // 16 KB @ 272 KB
  __bf16* xb           = (__bf16*)(ws + (1u << 20));           // 4 MB  @ 1 MB
  __bf16* hidden       = (__bf16*)(ws + (8u << 20));           // 8 MB  @ 8 MB
  (void)ws_size; (void)n_in; (void)in_sizes; (void)out_size;

  setup_kernel<<<NTOK / 4, 256, 0, stream>>>(x, rw, xb, top_pk, top_w, out);
  compact_kernel<<<NEXP, 256, 0, stream>>>(top_pk, counts, tok_list);
  up_kernel<<<640, 256, 0, stream>>>(xb, up, counts, tok_list, hidden);
  down_kernel<<<dim3(8, MAXMB), 256, 0, stream>>>(
      hidden, dw, counts, tok_list, top_w, out);
}